// Round 2
// baseline (545.779 us; speedup 1.0000x reference)
//
#include <hip/hip_runtime.h>
#include <hip/hip_fp16.h>

// Problem constants (fixed by the reference)
constexpr int NN    = 1024;  // tokens
constexpr int CZ    = 128;   // channels
constexpr int INDIM = 139;   // 4*32 + 2*2 + 7
// weight columns: [0,66) = pos, [66,132) = token, 132 = entity, [133,139) = chain

typedef float f4 __attribute__((ext_vector_type(4)));

// LDS tables (fp32, already fp16-quantized values):
//   P[66][128]  @ 0      (8448 floats)
//   T[66][128]  @ 8448   (8448 floats)
//   C[2][6][128]@ 16896  (1536 floats)  C[se][d_ch][c] = chain + se*entity
// total 18432 floats = 73728 B -> 2 blocks/CU on 160 KiB LDS

__global__ __launch_bounds__(256, 2) void relpos_kernel(
    const int* __restrict__ asym, const int* __restrict__ resi,
    const int* __restrict__ ent,  const int* __restrict__ tok,
    const int* __restrict__ sym,  const float* __restrict__ weight,
    float* __restrict__ out)
{
    __shared__ float lds[18432];
    float* P = lds;
    float* T = lds + 8448;
    float* C = lds + 16896;

    const int tid = threadIdx.x;

    // ---- build tables (fp16 round-to-nearest-even, back to fp32) ----
    for (int idx = tid; idx < 8448; idx += 256) {
        const int d = idx >> 7, c = idx & 127;
        P[idx] = __half2float(__float2half(weight[c * INDIM + d]));
        T[idx] = __half2float(__float2half(weight[c * INDIM + 66 + d]));
    }
    for (int idx = tid; idx < 768; idx += 256) {
        const int d = idx >> 7, c = idx & 127;
        const float ch = __half2float(__float2half(weight[c * INDIM + 133 + d]));
        const float en = __half2float(__float2half(weight[c * INDIM + 132]));
        C[idx]       = ch;        // same_ent == 0
        C[768 + idx] = ch + en;   // same_ent == 1
    }
    __syncthreads();

    // ---- block -> (row i, half of j) ----
    const int bid   = blockIdx.x;
    const int i     = bid >> 1;
    const int jbase = (bid & 1) << 9;  // 0 or 512

    const int ai = asym[i], ri = resi[i], ei = ent[i], ti = tok[i], si = sym[i];

    const int g  = tid >> 5;          // pair-group 0..7 (8 j's per iteration)
    const int c4 = (tid & 31) << 2;   // channel base, float4 per lane

    float* const out_row = out + ((size_t)i * NN) * CZ + c4;

    #pragma unroll 4
    for (int jt = 0; jt < 64; ++jt) {
        const int j  = jbase + jt * 8 + g;
        const int aj = asym[j], rj = resi[j], ej = ent[j], tj = tok[j], sj = sym[j];

        const bool sc = (ai == aj);
        const bool sr = (ri == rj);
        const int  se = (ei == ej) ? 1 : 0;

        int dres = min(max(ri - rj + 32, 0), 64);
        if (!sc) dres = 65;
        int dtok = min(max(ti - tj + 32, 0), 64);
        if (!(sc && sr)) dtok = 65;
        int dch = min(max(si - sj + 2, 0), 4);
        if (!se) dch = 5;

        const f4 p  = *(const f4*)&P[dres * 128 + c4];
        const f4 t  = *(const f4*)&T[dtok * 128 + c4];
        const f4 cc = *(const f4*)&C[se * 768 + dch * 128 + c4];

        f4 o = p + t + cc;

        __builtin_nontemporal_store(o, (f4*)(out_row + (size_t)j * CZ));
    }
}

extern "C" void kernel_launch(void* const* d_in, const int* in_sizes, int n_in,
                              void* d_out, int out_size, void* d_ws, size_t ws_size,
                              hipStream_t stream) {
    const int*   asym   = (const int*)d_in[0];
    const int*   resi   = (const int*)d_in[1];
    const int*   ent    = (const int*)d_in[2];
    const int*   tok    = (const int*)d_in[3];
    const int*   sym    = (const int*)d_in[4];
    const float* weight = (const float*)d_in[5];
    float*       out    = (float*)d_out;

    relpos_kernel<<<NN * 2, 256, 0, stream>>>(asym, resi, ent, tok, sym, weight, out);
}

// Round 3
// 530.684 us; speedup vs baseline: 1.0284x; 1.0284x over previous
//
#include <hip/hip_runtime.h>
#include <hip/hip_fp16.h>

// Problem constants (fixed by the reference)
constexpr int NN    = 1024;  // tokens
constexpr int CZ    = 128;   // channels
constexpr int INDIM = 139;   // 4*32 + 2*2 + 7
// weight columns: [0,66) = pos, [66,132) = token, 132 = entity, [133,139) = chain

typedef float f4 __attribute__((ext_vector_type(4)));

// d_ws layout:
//   [0, 73728)        fp32 tables: P[66][128] | T[66][128] | C[2][6][128]
//   [73728, 77824)    packed attrs, one uint32 per token:
//                     asym[2:0] ent[4:3] sym[6:5] resi[16:7] tok[28:17]
constexpr int TBL_FLOATS = 18432;   // 8448 + 8448 + 1536
constexpr int TBL_BYTES  = TBL_FLOATS * 4;

// ---------------- kernel A: build tables + packed attrs (once) -------------
__global__ void build_tables(const int* __restrict__ asym, const int* __restrict__ resi,
                             const int* __restrict__ ent,  const int* __restrict__ tok,
                             const int* __restrict__ sym,  const float* __restrict__ w,
                             float* __restrict__ tbl, unsigned* __restrict__ packed)
{
    const int gtid   = blockIdx.x * 256 + threadIdx.x;
    const int stride = gridDim.x * 256;

    for (int idx = gtid; idx < 8448; idx += stride) {
        const int d = idx >> 7, c = idx & 127;
        tbl[idx]        = __half2float(__float2half(w[c * INDIM + d]));
        tbl[8448 + idx] = __half2float(__float2half(w[c * INDIM + 66 + d]));
    }
    for (int idx = gtid; idx < 768; idx += stride) {
        const int d = idx >> 7, c = idx & 127;
        const float ch = __half2float(__float2half(w[c * INDIM + 133 + d]));
        const float en = __half2float(__float2half(w[c * INDIM + 132]));
        tbl[16896 + idx]       = ch;        // same_ent == 0
        tbl[16896 + 768 + idx] = ch + en;   // same_ent == 1
    }
    for (int j = gtid; j < NN; j += stride) {
        packed[j] = (unsigned)(asym[j] & 7)
                  | ((unsigned)(ent[j]  & 3)    << 3)
                  | ((unsigned)(sym[j]  & 3)    << 5)
                  | ((unsigned)(resi[j] & 1023) << 7)
                  | ((unsigned)(tok[j]  & 4095) << 17);
    }
}

// ---------------- kernel B: main streaming kernel --------------------------
__global__ __launch_bounds__(256, 2) void relpos_main(
    const float* __restrict__ tbl, const unsigned* __restrict__ packed,
    float* __restrict__ out)
{
    __shared__ __attribute__((aligned(16))) float    lds[TBL_FLOATS];
    __shared__ __attribute__((aligned(16))) unsigned attrs[512];

    const int tid = threadIdx.x;

    // coalesced contiguous table copy: 4608 float4, 18 per thread
    {
        const f4* __restrict__ src = (const f4*)tbl;
        f4* __restrict__ dst = (f4*)lds;
        #pragma unroll
        for (int k = 0; k < 18; ++k) dst[tid + 256 * k] = src[tid + 256 * k];
    }

    const int bid   = blockIdx.x;
    const int i     = bid >> 1;
    const int jbase = (bid & 1) << 9;  // 0 or 512

    for (int k = tid; k < 512; k += 256) attrs[k] = packed[jbase + k];
    __syncthreads();

    const unsigned pi = packed[i];   // 4 KiB, L2-hot, uniform per block
    const int ai = pi & 7, ei = (pi >> 3) & 3, si = (pi >> 5) & 3;
    const int ri = (pi >> 7) & 1023, ti = (pi >> 17) & 4095;

    const int g  = tid >> 5;          // pair-group 0..7 (8 j's per iteration)
    const int c4 = (tid & 31) << 2;   // channel base, float4 per lane

    float* outp = out + ((size_t)i << 17) + (size_t)(jbase + g) * CZ + c4;

    #pragma unroll 4
    for (int jt = 0; jt < 64; ++jt) {
        const unsigned pj = attrs[jt * 8 + g];
        const int aj = pj & 7, ej = (pj >> 3) & 3, sj = (pj >> 5) & 3;
        const int rj = (pj >> 7) & 1023, tj = (pj >> 17) & 4095;

        const bool sc = (ai == aj);
        const bool sr = (ri == rj);
        const int  se = (ei == ej) ? 1 : 0;

        int dres = min(max(ri - rj + 32, 0), 64);
        if (!sc) dres = 65;
        int dtok = min(max(ti - tj + 32, 0), 64);
        if (!(sc && sr)) dtok = 65;
        int dch = min(max(si - sj + 2, 0), 4);
        if (!se) dch = 5;

        const f4 p  = *(const f4*)&lds[dres * 128 + c4];
        const f4 t  = *(const f4*)&lds[8448 + dtok * 128 + c4];
        const f4 cc = *(const f4*)&lds[16896 + se * 768 + dch * 128 + c4];

        __builtin_nontemporal_store(p + t + cc, (f4*)outp);
        outp += 8 * CZ;   // advance 8 j-rows
    }
}

extern "C" void kernel_launch(void* const* d_in, const int* in_sizes, int n_in,
                              void* d_out, int out_size, void* d_ws, size_t ws_size,
                              hipStream_t stream) {
    const int*   asym   = (const int*)d_in[0];
    const int*   resi   = (const int*)d_in[1];
    const int*   ent    = (const int*)d_in[2];
    const int*   tok    = (const int*)d_in[3];
    const int*   sym    = (const int*)d_in[4];
    const float* weight = (const float*)d_in[5];
    float*       out    = (float*)d_out;

    float*    tbl    = (float*)d_ws;
    unsigned* packed = (unsigned*)((char*)d_ws + TBL_BYTES);

    build_tables<<<16, 256, 0, stream>>>(asym, resi, ent, tok, sym, weight, tbl, packed);
    relpos_main<<<NN * 2, 256, 0, stream>>>(tbl, packed, out);
}